// Round 1
// baseline (336.110 us; speedup 1.0000x reference)
//
#include <hip/hip_runtime.h>
#include <math.h>

#define FOURPI 12.566370614359172

// ---------------------------------------------------------------------------
// Main kernel: one thread per edge.
//   theta = atan2(||p x e||, p.e)         -> need cos/sin only (algebraic)
//   phi   = atan2(|cos t|*||p x e||, e_z * cos t)
//   Y_lm(theta, phi) for l in [0,6), 36 values, then out = Y @ K + bias
// ---------------------------------------------------------------------------
__global__ __launch_bounds__(256) void sph_edge_kernel(
    const float* __restrict__ env,    // [N,2,3]
    const float* __restrict__ Kmat,   // [36,64]
    const float* __restrict__ bias,   // [64]
    float* __restrict__ out,          // [N,64]
    int N)
{
    int e = blockIdx.x * 256 + threadIdx.x;
    if (e >= N) return;

    const float* p6 = env + (size_t)e * 6;
    float2 v0 = *reinterpret_cast<const float2*>(p6);
    float2 v1 = *reinterpret_cast<const float2*>(p6 + 2);
    float2 v2 = *reinterpret_cast<const float2*>(p6 + 4);
    float px = v0.x, py = v0.y, pz = v1.x;
    float ex = v1.y, ey = v2.x, ez = v2.y;

    // theta
    float dot_t = px*ex + py*ey + pz*ez;
    float cxv = py*ez - pz*ey;
    float cyv = pz*ex - px*ez;
    float czv = px*ey - py*ex;
    float cr2 = cxv*cxv + cyv*cyv + czv*czv;
    float cross_t = sqrtf(cr2);
    float r = sqrtf(dot_t*dot_t + cr2);
    float x = 1.f, s = 0.f;               // cos(theta), sin(theta)
    if (r > 0.f) { x = dot_t / r; s = cross_t / r; }

    // phi
    float dp = ez * x;
    float cp = fabsf(x) * cross_t;
    float rp = sqrtf(dp*dp + cp*cp);
    float c1 = 1.f, s1 = 0.f;             // cos(phi), sin(phi)
    if (rp > 0.f) { c1 = dp / rp; s1 = cp / rp; }

    // cos(m phi), sin(m phi) via Chebyshev recurrence
    float tc = 2.f * c1;
    float cm1 = c1,            sm1 = s1;
    float cm2 = tc*cm1 - 1.f,  sm2 = tc*sm1;
    float cm3 = tc*cm2 - cm1,  sm3 = tc*sm2 - sm1;
    float cm4 = tc*cm3 - cm2,  sm4 = tc*sm3 - sm2;
    float cm5 = tc*cm4 - cm3,  sm5 = tc*sm4 - sm3;

    // Associated Legendre P_l^m(cos theta), Condon-Shortley phase included
    float s2 = s*s, s3 = s2*s, s4 = s2*s2, s5 = s4*s;
    float P00 = 1.f;
    float P10 = x;
    float P11 = -s;
    float P20 = 1.5f*x*x - 0.5f;
    float P21 = -3.f*x*s;
    float P22 = 3.f*s2;
    float P30 = (5.f*x*P20 - 2.f*P10) * (1.f/3.f);
    float P31 = (5.f*x*P21 - 3.f*P11) * 0.5f;
    float P32 = 5.f*x*P22;
    float P33 = -15.f*s3;
    float P40 = (7.f*x*P30 - 3.f*P20) * 0.25f;
    float P41 = (7.f*x*P31 - 4.f*P21) * (1.f/3.f);
    float P42 = (7.f*x*P32 - 5.f*P22) * 0.5f;
    float P43 = 7.f*x*P33;
    float P44 = 105.f*s4;
    float P50 = (9.f*x*P40 - 4.f*P30) * 0.2f;
    float P51 = (9.f*x*P41 - 5.f*P31) * 0.25f;
    float P52 = (9.f*x*P42 - 6.f*P32) * (1.f/3.f);
    float P53 = (9.f*x*P43 - 7.f*P33) * 0.5f;
    float P54 = 9.f*x*P44;
    float P55 = -945.f*s5;

    // Normalization constants (compiler constant-folds the double sqrt)
    const float SQ2 = 1.4142135623730951f;
    const float K00 = (float)sqrt(1.0/FOURPI);
    const float K10 = (float)sqrt(3.0/FOURPI);
    const float K11 = (float)sqrt(3.0/FOURPI/2.0);
    const float K20 = (float)sqrt(5.0/FOURPI);
    const float K21 = (float)sqrt(5.0/FOURPI/6.0);
    const float K22 = (float)sqrt(5.0/FOURPI/24.0);
    const float K30 = (float)sqrt(7.0/FOURPI);
    const float K31 = (float)sqrt(7.0/FOURPI/12.0);
    const float K32 = (float)sqrt(7.0/FOURPI/120.0);
    const float K33 = (float)sqrt(7.0/FOURPI/720.0);
    const float K40 = (float)sqrt(9.0/FOURPI);
    const float K41 = (float)sqrt(9.0/FOURPI/20.0);
    const float K42 = (float)sqrt(9.0/FOURPI/360.0);
    const float K43 = (float)sqrt(9.0/FOURPI/5040.0);
    const float K44 = (float)sqrt(9.0/FOURPI/40320.0);
    const float K50 = (float)sqrt(11.0/FOURPI);
    const float K51 = (float)sqrt(11.0/FOURPI/30.0);
    const float K52 = (float)sqrt(11.0/FOURPI/840.0);
    const float K53 = (float)sqrt(11.0/FOURPI/20160.0);
    const float K54 = (float)sqrt(11.0/FOURPI/362880.0);
    const float K55 = (float)sqrt(11.0/FOURPI/3628800.0);

    float Y[36];
    // l=0
    Y[0]  = K00;
    // l=1: m=-1,0,1
    Y[1]  = SQ2*K11*sm1*P11;
    Y[2]  = K10*P10;
    Y[3]  = SQ2*K11*cm1*P11;
    // l=2
    Y[4]  = SQ2*K22*sm2*P22;
    Y[5]  = SQ2*K21*sm1*P21;
    Y[6]  = K20*P20;
    Y[7]  = SQ2*K21*cm1*P21;
    Y[8]  = SQ2*K22*cm2*P22;
    // l=3
    Y[9]  = SQ2*K33*sm3*P33;
    Y[10] = SQ2*K32*sm2*P32;
    Y[11] = SQ2*K31*sm1*P31;
    Y[12] = K30*P30;
    Y[13] = SQ2*K31*cm1*P31;
    Y[14] = SQ2*K32*cm2*P32;
    Y[15] = SQ2*K33*cm3*P33;
    // l=4
    Y[16] = SQ2*K44*sm4*P44;
    Y[17] = SQ2*K43*sm3*P43;
    Y[18] = SQ2*K42*sm2*P42;
    Y[19] = SQ2*K41*sm1*P41;
    Y[20] = K40*P40;
    Y[21] = SQ2*K41*cm1*P41;
    Y[22] = SQ2*K42*cm2*P42;
    Y[23] = SQ2*K43*cm3*P43;
    Y[24] = SQ2*K44*cm4*P44;
    // l=5
    Y[25] = SQ2*K55*sm5*P55;
    Y[26] = SQ2*K54*sm4*P54;
    Y[27] = SQ2*K53*sm3*P53;
    Y[28] = SQ2*K52*sm2*P52;
    Y[29] = SQ2*K51*sm1*P51;
    Y[30] = K50*P50;
    Y[31] = SQ2*K51*cm1*P51;
    Y[32] = SQ2*K52*cm2*P52;
    Y[33] = SQ2*K53*cm3*P53;
    Y[34] = SQ2*K54*cm4*P54;
    Y[35] = SQ2*K55*cm5*P55;

    // out[e, :] = Y @ Kmat + bias.  Kmat/bias indices are wave-uniform ->
    // scalar loads (constant cache); inner loop is pure v_fmac v,s,v.
    size_t ob = (size_t)e * 64;
    #pragma unroll
    for (int c0 = 0; c0 < 64; c0 += 16) {
        float acc[16];
        #pragma unroll
        for (int j = 0; j < 16; ++j) acc[j] = bias[c0 + j];
        #pragma unroll
        for (int k = 0; k < 36; ++k) {
            float yk = Y[k];
            #pragma unroll
            for (int j = 0; j < 16; ++j)
                acc[j] = fmaf(yk, Kmat[k*64 + c0 + j], acc[j]);
        }
        float4* o = reinterpret_cast<float4*>(out + ob + c0);
        o[0] = make_float4(acc[0],  acc[1],  acc[2],  acc[3]);
        o[1] = make_float4(acc[4],  acc[5],  acc[6],  acc[7]);
        o[2] = make_float4(acc[8],  acc[9],  acc[10], acc[11]);
        o[3] = make_float4(acc[12], acc[13], acc[14], acc[15]);
    }
}

// pair_indices (int) -> float values appended after the [N,64] output
__global__ __launch_bounds__(256) void idx_copy_kernel(
    const int4* __restrict__ idx, float* __restrict__ outp, int n4)
{
    int i = blockIdx.x * 256 + threadIdx.x;
    if (i < n4) {
        int4 v = idx[i];
        float4 f = make_float4((float)v.x, (float)v.y, (float)v.z, (float)v.w);
        reinterpret_cast<float4*>(outp)[i] = f;
    }
}

extern "C" void kernel_launch(void* const* d_in, const int* in_sizes, int n_in,
                              void* d_out, int out_size, void* d_ws, size_t ws_size,
                              hipStream_t stream) {
    const float* env  = (const float*)d_in[0];
    const int*   idx  = (const int*)d_in[1];
    const float* Kmat = (const float*)d_in[2];
    const float* bias = (const float*)d_in[3];
    float* out = (float*)d_out;

    int N = in_sizes[0] / 6;          // edges
    int nidx = in_sizes[1];           // N*2

    int blocks = (N + 255) / 256;
    sph_edge_kernel<<<blocks, 256, 0, stream>>>(env, Kmat, bias, out, N);

    int n4 = nidx / 4;
    int iblocks = (n4 + 255) / 256;
    idx_copy_kernel<<<iblocks, 256, 0, stream>>>(
        (const int4*)idx, out + (size_t)N * 64, n4);
}